// Round 1
// baseline (282.909 us; speedup 1.0000x reference)
//
#include <hip/hip_runtime.h>
#include <math.h>

// ---------------------------------------------------------------------------
// HDRL Poincare MLR, c=1.
//   out[b,o] = asinh( 2*sc / (|Bc*(1-x2)/Dd| * an + 1e-15) ) * an
//   sc = (Bc*xa - A*pa)/Dd,  A = 1-2px+x2, Dd = 1-2px+p2*x2, Bc = 1-p2
// px = <x_b, p_o>, xa = <x_b, a_o> via dual bf16 MFMA GEMM (shared x tiles).
// Stable identity: 1 - |mobius_add(-p,x)|^2 = Bc*(1-x2)/Dd  (no cancellation).
// ---------------------------------------------------------------------------

#define B_DIM 8192
#define O_DIM 4096
#define K_DIM 1024

using f32x4  = __attribute__((ext_vector_type(4))) float;
using bf16x8 = __attribute__((ext_vector_type(8))) short;

__device__ inline unsigned short f2bf(float f) {
  union { float f; unsigned u; } v; v.f = f;
  unsigned u = v.u;
  u += 0x7FFFu + ((u >> 16) & 1u);   // RNE
  return (unsigned short)(u >> 16);
}

__device__ inline void load_lds16(const void* g, void* l) {
  __builtin_amdgcn_global_load_lds(
      (const __attribute__((address_space(1))) void*)g,
      (__attribute__((address_space(3))) void*)l, 16, 0, 0);
}

// ---- per-output-row stats + bf16 conversion (weight & projected bias) -----
__global__ __launch_bounds__(256) void prep_rows(
    const float* __restrict__ wgt, const float* __restrict__ bia,
    unsigned short* __restrict__ a_bf, unsigned short* __restrict__ p_bf,
    float* __restrict__ p2v, float* __restrict__ pav, float* __restrict__ anv)
{
  const int o = blockIdx.x, t = threadIdx.x;
  const float4 w = ((const float4*)(wgt + (size_t)o * K_DIM))[t];
  const float4 b = ((const float4*)(bia + (size_t)o * K_DIM))[t];
  float a2 = w.x*w.x + w.y*w.y + w.z*w.z + w.w*w.w;
  float b2 = b.x*b.x + b.y*b.y + b.z*b.z + b.w*b.w;
  float ab = w.x*b.x + w.y*b.y + w.z*b.z + w.w*b.w;
  #pragma unroll
  for (int off = 32; off; off >>= 1) {
    a2 += __shfl_down(a2, off);
    b2 += __shfl_down(b2, off);
    ab += __shfl_down(ab, off);
  }
  __shared__ float sa[4], sb[4], sc_[4];
  const int wv = t >> 6, ln = t & 63;
  if (ln == 0) { sa[wv] = a2; sb[wv] = b2; sc_[wv] = ab; }
  __syncthreads();
  const float A2 = sa[0] + sa[1] + sa[2] + sa[3];
  const float B2 = sb[0] + sb[1] + sb[2] + sb[3];
  const float AB = sc_[0] + sc_[1] + sc_[2] + sc_[3];
  const float norm = sqrtf(B2);
  const float maxn = 1.0f - 1e-5f;            // (1-PROJ_EPS)/sqrt(c), c=1
  const float s = (norm > maxn) ? (maxn / norm) : 1.0f;
  if (t == 0) { p2v[o] = B2 * s * s; pav[o] = AB * s; anv[o] = sqrtf(A2); }
  unsigned short* ao = a_bf + (size_t)o * K_DIM + t * 4;
  unsigned short* po = p_bf + (size_t)o * K_DIM + t * 4;
  ao[0] = f2bf(w.x); ao[1] = f2bf(w.y); ao[2] = f2bf(w.z); ao[3] = f2bf(w.w);
  po[0] = f2bf(b.x * s); po[1] = f2bf(b.y * s); po[2] = f2bf(b.z * s); po[3] = f2bf(b.w * s);
}

// ---- per-batch-row stats + bf16 conversion of x ---------------------------
__global__ __launch_bounds__(256) void prep_x(
    const float* __restrict__ x, unsigned short* __restrict__ x_bf,
    float* __restrict__ x2v)
{
  const int bi = blockIdx.x, t = threadIdx.x;
  const float4 v = ((const float4*)(x + (size_t)bi * K_DIM))[t];
  float s2 = v.x*v.x + v.y*v.y + v.z*v.z + v.w*v.w;
  #pragma unroll
  for (int off = 32; off; off >>= 1) s2 += __shfl_down(s2, off);
  __shared__ float sl[4];
  const int wv = t >> 6, ln = t & 63;
  if (ln == 0) sl[wv] = s2;
  __syncthreads();
  if (t == 0) x2v[bi] = sl[0] + sl[1] + sl[2] + sl[3];
  unsigned short* xo = x_bf + (size_t)bi * K_DIM + t * 4;
  xo[0] = f2bf(v.x); xo[1] = f2bf(v.y); xo[2] = f2bf(v.z); xo[3] = f2bf(v.w);
}

// ---- main dual-GEMM + fused epilogue ---------------------------------------
// 128x128 tile, BK=64, 4 waves (each owns a 64x64 quadrant, 4x4 MFMA frags
// per output). global_load_lds width-16 staging (linear LDS, m97 structure).
__global__ __launch_bounds__(256, 2) void hdrl_main(
    const unsigned short* __restrict__ Xb,
    const unsigned short* __restrict__ Pb,
    const unsigned short* __restrict__ Ab,
    const float* __restrict__ x2v, const float* __restrict__ p2v,
    const float* __restrict__ pav, const float* __restrict__ anv,
    float* __restrict__ out)
{
  __shared__ unsigned short As[128 * 64];
  __shared__ unsigned short Ps[128 * 64];
  __shared__ unsigned short Ws[128 * 64];

  const int bid  = blockIdx.x;
  const int mt   = bid % (B_DIM / 128);       // 64 m-tiles
  const int nt   = bid / (B_DIM / 128);       // 32 n-tiles
  const int row0 = mt * 128, col0 = nt * 128;
  const int t    = threadIdx.x;
  const int wv   = t >> 6, lane = t & 63;
  const int wr   = (wv >> 1) * 64, wc = (wv & 1) * 64;
  const int lrow = lane & 15, kg = lane >> 4;

  f32x4 accp[4][4], acca[4][4];
  #pragma unroll
  for (int i = 0; i < 4; ++i)
    #pragma unroll
    for (int j = 0; j < 4; ++j) { accp[i][j] = (f32x4)0.0f; acca[i][j] = (f32x4)0.0f; }

  const int srow = lane >> 3;          // staging: row within 8-row chunk
  const int scol = (lane & 7) * 8;     // staging: bf16 col (×8 elems = 16 B)

  for (int kt = 0; kt < K_DIM / 64; ++kt) {
    const int k0 = kt * 64;
    #pragma unroll
    for (int q = 0; q < 4; ++q) {
      const int chunk = q * 4 + wv;                 // 0..15, wave-uniform
      const int r     = chunk * 8 + srow;           // 0..127
      const size_t ga = (size_t)(row0 + r) * K_DIM + k0 + scol;
      const size_t gb = (size_t)(col0 + r) * K_DIM + k0 + scol;
      const int    lo = chunk * 512;                // elements (1 KB chunks)
      load_lds16(Xb + ga, (void*)(As + lo));
      load_lds16(Pb + gb, (void*)(Ps + lo));
      load_lds16(Ab + gb, (void*)(Ws + lo));
    }
    __syncthreads();
    #pragma unroll
    for (int kk = 0; kk < 2; ++kk) {
      const int kb = kk * 32 + kg * 8;
      bf16x8 af[4], pf[4], wf[4];
      #pragma unroll
      for (int i = 0; i < 4; ++i)
        af[i] = *(const bf16x8*)&As[(wr + i * 16 + lrow) * 64 + kb];
      #pragma unroll
      for (int j = 0; j < 4; ++j) {
        pf[j] = *(const bf16x8*)&Ps[(wc + j * 16 + lrow) * 64 + kb];
        wf[j] = *(const bf16x8*)&Ws[(wc + j * 16 + lrow) * 64 + kb];
      }
      #pragma unroll
      for (int i = 0; i < 4; ++i)
        #pragma unroll
        for (int j = 0; j < 4; ++j) {
          accp[i][j] = __builtin_amdgcn_mfma_f32_16x16x32_bf16(af[i], pf[j], accp[i][j], 0, 0, 0);
          acca[i][j] = __builtin_amdgcn_mfma_f32_16x16x32_bf16(af[i], wf[j], acca[i][j], 0, 0, 0);
        }
    }
    __syncthreads();
  }

  // fused epilogue: C/D layout col = lane&15, row = (lane>>4)*4 + reg
  #pragma unroll
  for (int j = 0; j < 4; ++j) {
    const int col = col0 + wc + j * 16 + lrow;
    const float p2 = p2v[col], pa = pav[col], an = anv[col];
    const float Bc = 1.0f - p2;
    #pragma unroll
    for (int i = 0; i < 4; ++i) {
      const int rbase = row0 + wr + i * 16 + kg * 4;
      #pragma unroll
      for (int r = 0; r < 4; ++r) {
        const int row = rbase + r;
        const float x2 = x2v[row];
        const float px = accp[i][j][r];
        const float xa = acca[i][j][r];
        const float Aq = 1.0f - 2.0f * px + x2;
        const float Dd = 1.0f - 2.0f * px + p2 * x2;
        const float inv = 1.0f / Dd;
        const float sc = (Bc * xa - Aq * pa) * inv;
        const float dnm = fabsf(Bc * (1.0f - x2) * inv) * an + 1e-15f;
        out[(size_t)row * O_DIM + col] = asinhf(2.0f * sc / dnm) * an;
      }
    }
  }
}

extern "C" void kernel_launch(void* const* d_in, const int* in_sizes, int n_in,
                              void* d_out, int out_size, void* d_ws, size_t ws_size,
                              hipStream_t stream) {
  (void)in_sizes; (void)n_in; (void)out_size; (void)ws_size;
  const float* x = (const float*)d_in[0];
  const float* w = (const float*)d_in[1];
  const float* b = (const float*)d_in[2];
  float* out = (float*)d_out;

  char* ws = (char*)d_ws;
  unsigned short* x_bf = (unsigned short*)ws;                               // 16 MB
  unsigned short* p_bf = (unsigned short*)(ws + (size_t)16 * 1024 * 1024);  //  8 MB
  unsigned short* a_bf = (unsigned short*)(ws + (size_t)24 * 1024 * 1024);  //  8 MB
  float* p2v = (float*)(ws + (size_t)32 * 1024 * 1024);
  float* pav = p2v + O_DIM;
  float* anv = pav + O_DIM;
  float* x2v = anv + O_DIM;

  prep_rows<<<O_DIM, 256, 0, stream>>>(w, b, a_bf, p_bf, p2v, pav, anv);
  prep_x<<<B_DIM, 256, 0, stream>>>(x, x_bf, x2v);

  const int grid = (B_DIM / 128) * (O_DIM / 128);   // 2048
  hdrl_main<<<grid, 256, 0, stream>>>(x_bf, p_bf, a_bf, x2v, p2v, pav, anv, out);
}